// Round 9
// baseline (102.409 us; speedup 1.0000x reference)
//
#include <hip/hip_runtime.h>

// LSTM cell, B=4096, D=H=1024.
//   X = [inputs | h_prev]  (4096 x 2048) bf16   (ws, 16 MB)
//   Wct[g][h][k] = concat(W_g,U_g)^T bf16       (ws, 16 MB)
//   R9: 256x128 tile (4 gates x 32 h), 4 waves (2Mx2N, wave 128x64), BK=32
//   dbuf, 48 KiB LDS -> grid 512 = 2 independent blocks/CU (TLP hides the
//   intra-block read->MFMA serialization; R7 evidence). Same per-MAC LDS/
//   staging economics as the 256^2 kernel. R7's verified sync chain:
//   READ(buf) -> STAGE(buf^1) -> lgkm0 -> 32xMFMA -> vmcnt0 -> barrier.

typedef __attribute__((ext_vector_type(8))) short bfrag8;   // 8 bf16 (4 VGPRs)

__device__ __forceinline__ unsigned int f2bf(float f) {
  unsigned int u = __builtin_bit_cast(unsigned int, f);
  unsigned int r = (u + 0x7fffu + ((u >> 16) & 1u)) >> 16;
  return r & 0xffffu;
}

// ------------- fused prep: X cast/concat + W transpose/cast ------------------
__global__ __launch_bounds__(256) void prep_all(
    const float* __restrict__ inputs, const float* __restrict__ h_prev,
    const float* __restrict__ s0, const float* __restrict__ s1,
    const float* __restrict__ s2, const float* __restrict__ s3,
    const float* __restrict__ s4, const float* __restrict__ s5,
    const float* __restrict__ s6, const float* __restrict__ s7,
    unsigned short* __restrict__ X, unsigned short* __restrict__ Wct) {
  const int bidAll = blockIdx.x;
  const int tid = threadIdx.x;
  if (bidAll < 4096) {
    int idx = bidAll * 256 + tid;
    int b  = idx >> 8;
    int k8 = (idx & 255) * 8;
    const float* src = (k8 < 1024) ? (inputs + (size_t)b * 1024 + k8)
                                   : (h_prev + (size_t)b * 1024 + (k8 - 1024));
    float4 v0 = ((const float4*)src)[0];
    float4 v1 = ((const float4*)src)[1];
    uint4 o;
    o.x = f2bf(v0.x) | (f2bf(v0.y) << 16);
    o.y = f2bf(v0.z) | (f2bf(v0.w) << 16);
    o.z = f2bf(v1.x) | (f2bf(v1.y) << 16);
    o.w = f2bf(v1.z) | (f2bf(v1.w) << 16);
    *(uint4*)(X + (size_t)b * 2048 + k8) = o;
    return;
  }
  int blk = bidAll - 4096;
  int m = blk >> 8;
  const float* src = (m == 0) ? s0 : (m == 1) ? s1 : (m == 2) ? s2 : (m == 3) ? s3
                   : (m == 4) ? s4 : (m == 5) ? s5 : (m == 6) ? s6 : s7;
  int g = m >> 1, half = m & 1;
  unsigned short* dst = Wct + (size_t)g * 1024 * 2048 + (size_t)half * 1024;
  int t = blk & 255;
  int k0 = (t >> 4) * 64;
  int h0 = (t & 15) * 64;
  __shared__ float lt[64][68];
  #pragma unroll
  for (int it = 0; it < 4; ++it) {
    int r  = (tid >> 4) + it * 16;
    int c4 = (tid & 15) * 4;
    float4 v = *(const float4*)(src + (size_t)(k0 + r) * 1024 + h0 + c4);
    lt[r][c4 + 0] = v.x; lt[r][c4 + 1] = v.y; lt[r][c4 + 2] = v.z; lt[r][c4 + 3] = v.w;
  }
  __syncthreads();
  #pragma unroll
  for (int it = 0; it < 4; ++it) {
    int hh  = (tid >> 4) + it * 16;
    int kk4 = (tid & 15) * 4;
    uint2 o;
    o.x = f2bf(lt[kk4 + 0][hh]) | (f2bf(lt[kk4 + 1][hh]) << 16);
    o.y = f2bf(lt[kk4 + 2][hh]) | (f2bf(lt[kk4 + 3][hh]) << 16);
    *(uint2*)(dst + (size_t)(h0 + hh) * 2048 + k0 + kk4) = o;
  }
}

// ---------------- fused 4-gate GEMM + LSTM epilogue --------------------------
// LDS: A[buf][256 rows][32k*2B = 64 B] @0 (2 x 16 KiB), B[buf][128][64 B]
// @32768 (2 x 8 KiB). Swizzle: stored slot = logical_q ^ ((row>>1)&3);
// all 32 banks covered per wave64 b128 -> conflict-free (8 cyc class).

#define FENCE() asm volatile("" ::: "memory")
#define BARRIER() do { FENCE(); __builtin_amdgcn_s_barrier(); FENCE(); } while (0)
#define VMCNT0() asm volatile("s_waitcnt vmcnt(0)" ::: "memory")
#define LGKM0() asm volatile("s_waitcnt lgkmcnt(0)" ::: "memory")
#define GLOAD16(gp, lp) __builtin_amdgcn_global_load_lds( \
    (const __attribute__((address_space(1))) unsigned int*)(gp), \
    (__attribute__((address_space(3))) unsigned int*)(lp), 16, 0, 0)
#define DSR(dst, addr, off) asm volatile("ds_read_b128 %0, %1 offset:%c2" \
    : "=v"(dst) : "v"(addr), "n"(off))

// full AGPR clobber list (keeps the allocator out of a0-a127)
#define AC "a0","a1","a2","a3","a4","a5","a6","a7","a8","a9","a10","a11","a12","a13","a14","a15", \
 "a16","a17","a18","a19","a20","a21","a22","a23","a24","a25","a26","a27","a28","a29","a30","a31", \
 "a32","a33","a34","a35","a36","a37","a38","a39","a40","a41","a42","a43","a44","a45","a46","a47", \
 "a48","a49","a50","a51","a52","a53","a54","a55","a56","a57","a58","a59","a60","a61","a62","a63", \
 "a64","a65","a66","a67","a68","a69","a70","a71","a72","a73","a74","a75","a76","a77","a78","a79", \
 "a80","a81","a82","a83","a84","a85","a86","a87","a88","a89","a90","a91","a92","a93","a94","a95", \
 "a96","a97","a98","a99","a100","a101","a102","a103","a104","a105","a106","a107","a108","a109","a110","a111", \
 "a112","a113","a114","a115","a116","a117","a118","a119","a120","a121","a122","a123","a124","a125","a126","a127"

#define WZ(n) "v_accvgpr_write_b32 a" #n ", 0\n\t"
#define AINIT() asm volatile( \
 WZ(0)WZ(1)WZ(2)WZ(3)WZ(4)WZ(5)WZ(6)WZ(7)WZ(8)WZ(9)WZ(10)WZ(11)WZ(12)WZ(13)WZ(14)WZ(15) \
 WZ(16)WZ(17)WZ(18)WZ(19)WZ(20)WZ(21)WZ(22)WZ(23)WZ(24)WZ(25)WZ(26)WZ(27)WZ(28)WZ(29)WZ(30)WZ(31) \
 WZ(32)WZ(33)WZ(34)WZ(35)WZ(36)WZ(37)WZ(38)WZ(39)WZ(40)WZ(41)WZ(42)WZ(43)WZ(44)WZ(45)WZ(46)WZ(47) \
 WZ(48)WZ(49)WZ(50)WZ(51)WZ(52)WZ(53)WZ(54)WZ(55)WZ(56)WZ(57)WZ(58)WZ(59)WZ(60)WZ(61)WZ(62)WZ(63) \
 WZ(64)WZ(65)WZ(66)WZ(67)WZ(68)WZ(69)WZ(70)WZ(71)WZ(72)WZ(73)WZ(74)WZ(75)WZ(76)WZ(77)WZ(78)WZ(79) \
 WZ(80)WZ(81)WZ(82)WZ(83)WZ(84)WZ(85)WZ(86)WZ(87)WZ(88)WZ(89)WZ(90)WZ(91)WZ(92)WZ(93)WZ(94)WZ(95) \
 WZ(96)WZ(97)WZ(98)WZ(99)WZ(100)WZ(101)WZ(102)WZ(103)WZ(104)WZ(105)WZ(106)WZ(107)WZ(108)WZ(109)WZ(110)WZ(111) \
 WZ(112)WZ(113)WZ(114)WZ(115)WZ(116)WZ(117)WZ(118)WZ(119)WZ(120)WZ(121)WZ(122)WZ(123)WZ(124)WZ(125)WZ(126)WZ(127) \
 ::: AC)

#define MFMA_ONE(BR, AF, BF) asm volatile( \
    "v_mfma_f32_16x16x32_bf16 a[" BR "], %0, %1, a[" BR "]" \
    :: "v"(AF), "v"(BF) : AC)

// 32 MFMA: acc[g][m] += Af[m]*Bf[g], AGPR base (g*8+m)*4
#define CL32() do { \
  __builtin_amdgcn_s_setprio(1); \
  MFMA_ONE("0:3",    Af[0], Bf[0]); MFMA_ONE("4:7",    Af[1], Bf[0]); \
  MFMA_ONE("8:11",   Af[2], Bf[0]); MFMA_ONE("12:15",  Af[3], Bf[0]); \
  MFMA_ONE("16:19",  Af[4], Bf[0]); MFMA_ONE("20:23",  Af[5], Bf[0]); \
  MFMA_ONE("24:27",  Af[6], Bf[0]); MFMA_ONE("28:31",  Af[7], Bf[0]); \
  MFMA_ONE("32:35",  Af[0], Bf[1]); MFMA_ONE("36:39",  Af[1], Bf[1]); \
  MFMA_ONE("40:43",  Af[2], Bf[1]); MFMA_ONE("44:47",  Af[3], Bf[1]); \
  MFMA_ONE("48:51",  Af[4], Bf[1]); MFMA_ONE("52:55",  Af[5], Bf[1]); \
  MFMA_ONE("56:59",  Af[6], Bf[1]); MFMA_ONE("60:63",  Af[7], Bf[1]); \
  MFMA_ONE("64:67",  Af[0], Bf[2]); MFMA_ONE("68:71",  Af[1], Bf[2]); \
  MFMA_ONE("72:75",  Af[2], Bf[2]); MFMA_ONE("76:79",  Af[3], Bf[2]); \
  MFMA_ONE("80:83",  Af[4], Bf[2]); MFMA_ONE("84:87",  Af[5], Bf[2]); \
  MFMA_ONE("88:91",  Af[6], Bf[2]); MFMA_ONE("92:95",  Af[7], Bf[2]); \
  MFMA_ONE("96:99",  Af[0], Bf[3]); MFMA_ONE("100:103",Af[1], Bf[3]); \
  MFMA_ONE("104:107",Af[2], Bf[3]); MFMA_ONE("108:111",Af[3], Bf[3]); \
  MFMA_ONE("112:115",Af[4], Bf[3]); MFMA_ONE("116:119",Af[5], Bf[3]); \
  MFMA_ONE("120:123",Af[6], Bf[3]); MFMA_ONE("124:127",Af[7], Bf[3]); \
  __builtin_amdgcn_s_setprio(0); \
} while (0)

#define READ_A(BUF) do { \
  DSR(Af[0], aA, (BUF)*16384 + 0);    DSR(Af[1], aA, (BUF)*16384 + 1024); \
  DSR(Af[2], aA, (BUF)*16384 + 2048); DSR(Af[3], aA, (BUF)*16384 + 3072); \
  DSR(Af[4], aA, (BUF)*16384 + 4096); DSR(Af[5], aA, (BUF)*16384 + 5120); \
  DSR(Af[6], aA, (BUF)*16384 + 6144); DSR(Af[7], aA, (BUF)*16384 + 7168); \
} while (0)

#define READ_B(BUF) do { \
  DSR(Bf[0], aB, (BUF)*8192 + 0);    DSR(Bf[1], aB, (BUF)*8192 + 1024); \
  DSR(Bf[2], aB, (BUF)*8192 + 2048); DSR(Bf[3], aB, (BUF)*8192 + 3072); \
} while (0)

#define STAGE(BUF, kt) do { int _kb = ((kt) < 64 ? (kt) : 63) * 32; \
  GLOAD16(pA0 + _kb, smem + (BUF)*16384 + dA0); \
  GLOAD16(pA1 + _kb, smem + (BUF)*16384 + dA1); \
  GLOAD16(pA2 + _kb, smem + (BUF)*16384 + dA2); \
  GLOAD16(pA3 + _kb, smem + (BUF)*16384 + dA3); \
  GLOAD16(pB0 + _kb, smem + 32768 + (BUF)*8192 + dB0); \
  GLOAD16(pB1 + _kb, smem + 32768 + (BUF)*8192 + dB1); \
} while (0)

#define ARD(X, RS) asm volatile("v_accvgpr_read_b32 %0, " RS : "=v"(X))

#define EPI_M(Mi, F0,F1,F2,F3, I0,I1,I2,I3, C0,C1,C2,C3, O0,O1,O2,O3) do { \
  float pf[4], pi[4], pc[4], po[4]; \
  ARD(pf[0],F0); ARD(pf[1],F1); ARD(pf[2],F2); ARD(pf[3],F3); \
  ARD(pi[0],I0); ARD(pi[1],I1); ARD(pi[2],I2); ARD(pi[3],I3); \
  ARD(pc[0],C0); ARD(pc[1],C1); ARD(pc[2],C2); ARD(pc[3],C3); \
  ARD(po[0],O0); ARD(po[1],O1); ARD(po[2],O2); ARD(po[3],O3); \
  _Pragma("unroll") for (int j = 0; j < 4; ++j) { \
    const int b = rbw + (Mi) * 16 + q * 4 + j; \
    float xf = pf[j] + Bgf, xi = pi[j] + Bgi, xc = pc[j] + Bgc, xo = po[j] + Bgo; \
    float fg = 1.f / (1.f + __expf(-xf)); \
    float ig = 1.f / (1.f + __expf(-xi)); \
    float ct = 2.f / (1.f + __expf(-2.f * xc)) - 1.f; \
    float og = 1.f / (1.f + __expf(-xo)); \
    float cn = fg * c_prev[(size_t)b * 1024 + hcol] + ig * ct; \
    float hn = og * (2.f / (1.f + __expf(-2.f * cn)) - 1.f); \
    out[(size_t)b * 1024 + hcol] = hn; \
    out[(size_t)4194304 + (size_t)b * 1024 + hcol] = cn; \
  } \
} while (0)

__global__ __launch_bounds__(256, 2) void lstm_gemm(
    const unsigned short* __restrict__ X, const unsigned short* __restrict__ Wct,
    const float* __restrict__ c_prev,
    const float* __restrict__ bfv, const float* __restrict__ biv,
    const float* __restrict__ bcv, const float* __restrict__ bov,
    float* __restrict__ out) {
  extern __shared__ __align__(16) char smem[];
  const int tid = threadIdx.x;
  const int lane = tid & 63, w = tid >> 6;    // 4 waves
  const int u = lane & 15, q = (lane >> 4) & 3;
  const int wm = w >> 1, wn = w & 1;          // 2M x 2N, wave tile 128x64

  // XCD map: xcd owns 2 M-panels x all 32 N-tiles (A L2-resident, B L2-shared)
  const int bid = blockIdx.x;
  const int xcd = bid & 7, idx = bid >> 3;    // idx in [0,64)
  const int row0 = (xcd * 2 + (idx & 1)) * 256;
  const int h0 = (idx >> 1) * 32;             // 32 h per block

  const unsigned lds0 = (unsigned)(size_t)((__attribute__((address_space(3))) char*)smem);

  // fragment read bases: row stride 64 B; swz slot = q ^ ((row>>1)&3),
  // (row>>1)&3 == (u>>1)&3 for both A rows (wm*128+m*16+u) and B rows.
  const int fsw = (q ^ ((u >> 1) & 3)) << 4;
  const unsigned aA = lds0 + (wm * 128 + u) * 64 + fsw;
  const unsigned aB = lds0 + 32768 + (wn * 64 + u) * 64 + fsw;

  // staging: instr slot s covers chunks [s*64, s*64+64); chunk c -> row c>>2,
  // slot c&3; source octet = (c&3) ^ ((row>>1)&3), (row>>1)&3 == (l4>>1)&3.
  const int l4 = lane >> 2;
  const int ss = (lane & 3) ^ ((l4 >> 1) & 3);
  const int sA0 = 0 * 4 + w, sA1 = 1 * 4 + w, sA2 = 2 * 4 + w, sA3 = 3 * 4 + w;
  const int sB0 = 0 * 4 + w, sB1 = 1 * 4 + w;
  const int dA0 = sA0 * 1024 + lane * 16, dA1 = sA1 * 1024 + lane * 16;
  const int dA2 = sA2 * 1024 + lane * 16, dA3 = sA3 * 1024 + lane * 16;
  const int dB0 = sB0 * 1024 + lane * 16, dB1 = sB1 * 1024 + lane * 16;
  const unsigned short* pA0 = X + (size_t)(row0 + sA0 * 16 + l4) * 2048 + ss * 8;
  const unsigned short* pA1 = X + (size_t)(row0 + sA1 * 16 + l4) * 2048 + ss * 8;
  const unsigned short* pA2 = X + (size_t)(row0 + sA2 * 16 + l4) * 2048 + ss * 8;
  const unsigned short* pA3 = X + (size_t)(row0 + sA3 * 16 + l4) * 2048 + ss * 8;
  auto wrow = [&](int C) { return (((C >> 4) & 3) << 10) + h0 + ((C >> 6) << 4) + (C & 15); };
  const unsigned short* pB0 = Wct + (size_t)wrow(sB0 * 16 + l4) * 2048 + ss * 8;
  const unsigned short* pB1 = Wct + (size_t)wrow(sB1 * 16 + l4) * 2048 + ss * 8;

  AINIT();
  bfrag8 Af[8], Bf[4];

  // prologue: stage K-tile 0 into buf0
  STAGE(0, 0);
  VMCNT0();
  BARRIER();

  #pragma unroll 1
  for (int tt = 0; tt < 32; ++tt) {
    const int t1 = 2 * tt + 1, t2 = 2 * tt + 2;
    // even K-tile: read buf0, stage t1 -> buf1
    READ_A(0); READ_B(0);
    STAGE(1, t1);
    LGKM0();
    CL32();
    VMCNT0();
    BARRIER();
    // odd K-tile: read buf1, stage t2 -> buf0 (clamped at end; never read)
    READ_A(1); READ_B(1);
    STAGE(0, t2);
    LGKM0();
    CL32();
    VMCNT0();
    BARRIER();
  }
  LGKM0();
  asm volatile("s_nop 7\n\ts_nop 7");   // MFMA -> accvgpr_read hazard guard

  // epilogue: B col c = wn*64 + g*16 + u -> gate g, h = h0 + wn*16 + u
  const int hcol = h0 + wn * 16 + u;
  const float Bgf = bfv[hcol], Bgi = biv[hcol], Bgc = bcv[hcol], Bgo = bov[hcol];
  const int rbw = row0 + wm * 128;
  EPI_M(0, "a0","a1","a2","a3",     "a32","a33","a34","a35",
           "a64","a65","a66","a67", "a96","a97","a98","a99");
  EPI_M(1, "a4","a5","a6","a7",     "a36","a37","a38","a39",
           "a68","a69","a70","a71", "a100","a101","a102","a103");
  EPI_M(2, "a8","a9","a10","a11",   "a40","a41","a42","a43",
           "a72","a73","a74","a75", "a104","a105","a106","a107");
  EPI_M(3, "a12","a13","a14","a15", "a44","a45","a46","a47",
           "a76","a77","a78","a79", "a108","a109","a110","a111");
  EPI_M(4, "a16","a17","a18","a19", "a48","a49","a50","a51",
           "a80","a81","a82","a83", "a112","a113","a114","a115");
  EPI_M(5, "a20","a21","a22","a23", "a52","a53","a54","a55",
           "a84","a85","a86","a87", "a116","a117","a118","a119");
  EPI_M(6, "a24","a25","a26","a27", "a56","a57","a58","a59",
           "a88","a89","a90","a91", "a120","a121","a122","a123");
  EPI_M(7, "a28","a29","a30","a31", "a60","a61","a62","a63",
           "a92","a93","a94","a95", "a124","a125","a126","a127");
}

extern "C" void kernel_launch(void* const* d_in, const int* in_sizes, int n_in,
                              void* d_out, int out_size, void* d_ws, size_t ws_size,
                              hipStream_t stream) {
  const float* inputs = (const float*)d_in[0];
  const float* h_prev = (const float*)d_in[1];
  const float* c_prev = (const float*)d_in[2];
  const float* Wf = (const float*)d_in[3];
  const float* Uf = (const float*)d_in[4];
  const float* bf = (const float*)d_in[5];
  const float* Wi = (const float*)d_in[6];
  const float* Ui = (const float*)d_in[7];
  const float* bi = (const float*)d_in[8];
  const float* Wc = (const float*)d_in[9];
  const float* Uc = (const float*)d_in[10];
  const float* bc = (const float*)d_in[11];
  const float* Wo = (const float*)d_in[12];
  const float* Uo = (const float*)d_in[13];
  const float* bo = (const float*)d_in[14];
  float* out = (float*)d_out;

  unsigned short* X   = (unsigned short*)d_ws;                 // 16 MB
  unsigned short* Wct = X + (size_t)4096 * 2048;               // 16 MB

  (void)hipFuncSetAttribute(reinterpret_cast<const void*>(lstm_gemm),
                            hipFuncAttributeMaxDynamicSharedMemorySize, 49152);

  prep_all<<<6144, 256, 0, stream>>>(inputs, h_prev,
                                     Wf, Uf, Wi, Ui, Wc, Uc, Wo, Uo, X, Wct);
  lstm_gemm<<<512, 256, 49152, stream>>>(X, Wct, c_prev, bf, bi, bc, bo, out);
}

// Round 11
// 94.289 us; speedup vs baseline: 1.0861x; 1.0861x over previous
//
#include <hip/hip_runtime.h>

// LSTM cell, B=4096, D=H=1024.
//   X = [inputs | h_prev]  (4096 x 2048) bf16   (ws, 16 MB)
//   Wct[g][h][k] = concat(W_g,U_g)^T bf16       (ws, 16 MB)
//   8-phase 256x256 fused GEMM (4 gates x 64 h per block) + LSTM epilogue.
//   R11 = R10 with the epilogue gate-exchange switched from raw ds_swizzle
//   (+manual lgkmcnt -> rule-#18 hoist bug) to __shfl_xor (compiler-managed
//   waits). Main loop identical to R8's verified skeleton, MFMA = 32x32x16.

typedef __attribute__((ext_vector_type(8))) short bfrag8;   // 8 bf16 (4 VGPRs)

__device__ __forceinline__ unsigned int f2bf(float f) {
  unsigned int u = __builtin_bit_cast(unsigned int, f);
  unsigned int r = (u + 0x7fffu + ((u >> 16) & 1u)) >> 16;
  return r & 0xffffu;
}

// ---------------- prep X: [inputs | h_prev] -> bf16 (4096 x 2048) ------------
__global__ __launch_bounds__(256) void prep_x(const float* __restrict__ inputs,
                                              const float* __restrict__ h_prev,
                                              unsigned short* __restrict__ X) {
  int idx = blockIdx.x * 256 + threadIdx.x;
  int b  = idx >> 8;
  int k8 = (idx & 255) * 8;
  const float* src = (k8 < 1024) ? (inputs + (size_t)b * 1024 + k8)
                                 : (h_prev + (size_t)b * 1024 + (k8 - 1024));
  float4 v0 = ((const float4*)src)[0];
  float4 v1 = ((const float4*)src)[1];
  uint4 o;
  o.x = f2bf(v0.x) | (f2bf(v0.y) << 16);
  o.y = f2bf(v0.z) | (f2bf(v0.w) << 16);
  o.z = f2bf(v1.x) | (f2bf(v1.y) << 16);
  o.w = f2bf(v1.z) | (f2bf(v1.w) << 16);
  *(uint4*)(X + (size_t)b * 2048 + k8) = o;
}

// ------------- prep W: transpose+cast 8x (1024x1024 f32) -> Wct[g][h][k] -----
__global__ __launch_bounds__(256) void prep_w(
    const float* __restrict__ s0, const float* __restrict__ s1,
    const float* __restrict__ s2, const float* __restrict__ s3,
    const float* __restrict__ s4, const float* __restrict__ s5,
    const float* __restrict__ s6, const float* __restrict__ s7,
    unsigned short* __restrict__ Wct) {
  int blk = blockIdx.x;
  int m = blk >> 8;
  const float* src = (m == 0) ? s0 : (m == 1) ? s1 : (m == 2) ? s2 : (m == 3) ? s3
                   : (m == 4) ? s4 : (m == 5) ? s5 : (m == 6) ? s6 : s7;
  int g = m >> 1, half = m & 1;
  unsigned short* dst = Wct + (size_t)g * 1024 * 2048 + (size_t)half * 1024;
  int t = blk & 255;
  int k0 = (t >> 4) * 64;
  int h0 = (t & 15) * 64;
  __shared__ float lt[64][68];
  int tid = threadIdx.x;
  #pragma unroll
  for (int it = 0; it < 4; ++it) {
    int r  = (tid >> 4) + it * 16;
    int c4 = (tid & 15) * 4;
    float4 v = *(const float4*)(src + (size_t)(k0 + r) * 1024 + h0 + c4);
    lt[r][c4 + 0] = v.x; lt[r][c4 + 1] = v.y; lt[r][c4 + 2] = v.z; lt[r][c4 + 3] = v.w;
  }
  __syncthreads();
  #pragma unroll
  for (int it = 0; it < 4; ++it) {
    int hh  = (tid >> 4) + it * 16;
    int kk4 = (tid & 15) * 4;
    uint2 o;
    o.x = f2bf(lt[kk4 + 0][hh]) | (f2bf(lt[kk4 + 1][hh]) << 16);
    o.y = f2bf(lt[kk4 + 2][hh]) | (f2bf(lt[kk4 + 3][hh]) << 16);
    *(uint2*)(dst + (size_t)(h0 + hh) * 2048 + k0 + kk4) = o;
  }
}

// ---------------- 8-phase fused 4-gate GEMM + LSTM epilogue ------------------

#define FENCE() asm volatile("" ::: "memory")
#define BARRIER() do { FENCE(); __builtin_amdgcn_s_barrier(); FENCE(); } while (0)
#define VMCNT(n) asm volatile("s_waitcnt vmcnt(" #n ")" ::: "memory")
#define LGKM(n) asm volatile("s_waitcnt lgkmcnt(" #n ")" ::: "memory")
#define GLOAD16(gp, lp) __builtin_amdgcn_global_load_lds( \
    (const __attribute__((address_space(1))) unsigned int*)(gp), \
    (__attribute__((address_space(3))) unsigned int*)(lp), 16, 0, 0)
#define DSR(dst, addr, off) asm volatile("ds_read_b128 %0, %1 offset:%c2" \
    : "=v"(dst) : "v"(addr), "n"(off))

// full AGPR clobber list (keeps the allocator out of a0-a127)
#define AC "a0","a1","a2","a3","a4","a5","a6","a7","a8","a9","a10","a11","a12","a13","a14","a15", \
 "a16","a17","a18","a19","a20","a21","a22","a23","a24","a25","a26","a27","a28","a29","a30","a31", \
 "a32","a33","a34","a35","a36","a37","a38","a39","a40","a41","a42","a43","a44","a45","a46","a47", \
 "a48","a49","a50","a51","a52","a53","a54","a55","a56","a57","a58","a59","a60","a61","a62","a63", \
 "a64","a65","a66","a67","a68","a69","a70","a71","a72","a73","a74","a75","a76","a77","a78","a79", \
 "a80","a81","a82","a83","a84","a85","a86","a87","a88","a89","a90","a91","a92","a93","a94","a95", \
 "a96","a97","a98","a99","a100","a101","a102","a103","a104","a105","a106","a107","a108","a109","a110","a111", \
 "a112","a113","a114","a115","a116","a117","a118","a119","a120","a121","a122","a123","a124","a125","a126","a127"

#define WZ(n) "v_accvgpr_write_b32 a" #n ", 0\n\t"
#define AINIT() asm volatile( \
 WZ(0)WZ(1)WZ(2)WZ(3)WZ(4)WZ(5)WZ(6)WZ(7)WZ(8)WZ(9)WZ(10)WZ(11)WZ(12)WZ(13)WZ(14)WZ(15) \
 WZ(16)WZ(17)WZ(18)WZ(19)WZ(20)WZ(21)WZ(22)WZ(23)WZ(24)WZ(25)WZ(26)WZ(27)WZ(28)WZ(29)WZ(30)WZ(31) \
 WZ(32)WZ(33)WZ(34)WZ(35)WZ(36)WZ(37)WZ(38)WZ(39)WZ(40)WZ(41)WZ(42)WZ(43)WZ(44)WZ(45)WZ(46)WZ(47) \
 WZ(48)WZ(49)WZ(50)WZ(51)WZ(52)WZ(53)WZ(54)WZ(55)WZ(56)WZ(57)WZ(58)WZ(59)WZ(60)WZ(61)WZ(62)WZ(63) \
 WZ(64)WZ(65)WZ(66)WZ(67)WZ(68)WZ(69)WZ(70)WZ(71)WZ(72)WZ(73)WZ(74)WZ(75)WZ(76)WZ(77)WZ(78)WZ(79) \
 WZ(80)WZ(81)WZ(82)WZ(83)WZ(84)WZ(85)WZ(86)WZ(87)WZ(88)WZ(89)WZ(90)WZ(91)WZ(92)WZ(93)WZ(94)WZ(95) \
 WZ(96)WZ(97)WZ(98)WZ(99)WZ(100)WZ(101)WZ(102)WZ(103)WZ(104)WZ(105)WZ(106)WZ(107)WZ(108)WZ(109)WZ(110)WZ(111) \
 WZ(112)WZ(113)WZ(114)WZ(115)WZ(116)WZ(117)WZ(118)WZ(119)WZ(120)WZ(121)WZ(122)WZ(123)WZ(124)WZ(125)WZ(126)WZ(127) \
 ::: AC)

#define M32(BR, AF, BF) asm volatile( \
    "v_mfma_f32_32x32x16_bf16 a[" BR "], %0, %1, a[" BR "]" \
    :: "v"(AF), "v"(BF) : AC)

// 8 MFMA (2 ksteps x 2 mt x 2 nt). A4: [m*2+ks], B4: [nt*2+ks].
// Same-acc reuse distance = 4 MFMA.
#define CL8(A4, B4, T00, T01, T10, T11) do { \
  __builtin_amdgcn_s_setprio(1); \
  M32(T00, (A4)[0], (B4)[0]); M32(T01, (A4)[2], (B4)[0]); \
  M32(T10, (A4)[0], (B4)[2]); M32(T11, (A4)[2], (B4)[2]); \
  M32(T00, (A4)[1], (B4)[1]); M32(T01, (A4)[3], (B4)[1]); \
  M32(T10, (A4)[1], (B4)[3]); M32(T11, (A4)[3], (B4)[3]); \
  __builtin_amdgcn_s_setprio(0); \
} while (0)

// tile T(nt, mt) AGPR base = (nt*4+mt)*16
#define CL_MH0(A4, B4) CL8(A4, B4, "0:15",  "16:31", "64:79",  "80:95")
#define CL_MH1(A4, B4) CL8(A4, B4, "32:47", "48:63", "96:111", "112:127")

// A frag (mt = MH*2+m, ks = KH*2+k): addr vA[ks], offset mt*4096 (+buf)
#define READ_A4(arr, BUF, MH, KH) do { \
  DSR(arr[0], vA[2*(KH)+0], (BUF)*32768 + ((MH)*2+0)*4096); \
  DSR(arr[1], vA[2*(KH)+1], (BUF)*32768 + ((MH)*2+0)*4096); \
  DSR(arr[2], vA[2*(KH)+0], (BUF)*32768 + ((MH)*2+1)*4096); \
  DSR(arr[3], vA[2*(KH)+1], (BUF)*32768 + ((MH)*2+1)*4096); \
} while (0)

// B frag (nt, ks = KH*2+k): addr vB[ks], offset nt*4096 (+buf)
#define READ_B4(arr, BUF, KH) do { \
  DSR(arr[0], vB[2*(KH)+0], (BUF)*32768 + 0);    \
  DSR(arr[1], vB[2*(KH)+1], (BUF)*32768 + 0);    \
  DSR(arr[2], vB[2*(KH)+0], (BUF)*32768 + 4096); \
  DSR(arr[3], vB[2*(KH)+1], (BUF)*32768 + 4096); \
} while (0)

#define STAGE_A(BUF, H, kt) do { int _kb = ((kt) < 32 ? (kt) : 31) * 64; \
  GLOAD16(pA0 + (size_t)(H) * 262144 + _kb, smem + (BUF)*32768 + (H)*16384 + stbase); \
  GLOAD16(pA1 + (size_t)(H) * 262144 + _kb, smem + (BUF)*32768 + (H)*16384 + stbase + 1024); \
} while (0)

#define STAGE_B(BUF, kt) do { int _kb = ((kt) < 32 ? (kt) : 31) * 64; \
  GLOAD16(pB00 + _kb, smem + 65536 + (BUF)*32768 + stbase); \
  GLOAD16(pB01 + _kb, smem + 65536 + (BUF)*32768 + stbase + 1024); \
  GLOAD16(pB10 + _kb, smem + 65536 + (BUF)*32768 + 16384 + stbase); \
  GLOAD16(pB11 + _kb, smem + 65536 + (BUF)*32768 + 16384 + stbase + 1024); \
} while (0)

#define ARD(X, RS) asm volatile("v_accvgpr_read_b32 %0, " RS : "=v"(X))

#define ARD16(arr, N0,N1,N2,N3,N4,N5,N6,N7,N8,N9,NA,NB,NC,ND,NE,NF) do { \
  ARD(arr[0],N0); ARD(arr[1],N1); ARD(arr[2],N2); ARD(arr[3],N3); \
  ARD(arr[4],N4); ARD(arr[5],N5); ARD(arr[6],N6); ARD(arr[7],N7); \
  ARD(arr[8],N8); ARD(arr[9],N9); ARD(arr[10],NA); ARD(arr[11],NB); \
  ARD(arr[12],NC); ARD(arr[13],ND); ARD(arr[14],NE); ARD(arr[15],NF); \
} while (0)

// epilogue per mt: own nt0 = gate g1, own nt1 = gate g1+2 (g1 = lane bit4).
// lane^16 holds the complementary gates at the same h, same row set.
// g0 lanes finalize regs 0..7 (rows {0..3,8..11}+4h5), g1 lanes regs 8..15
// (rows {16..19,24..27}+4h5). Exchange via __shfl_xor (compiler-managed
// waits — rule #18 fix vs R10's raw ds_swizzle).
#define EPI_MT(MT) do { \
  float o0[16], o1[16], r0[8], r1[8]; \
  if ((MT) == 0) { ARD16(o0,"a0","a1","a2","a3","a4","a5","a6","a7","a8","a9","a10","a11","a12","a13","a14","a15"); \
                   ARD16(o1,"a64","a65","a66","a67","a68","a69","a70","a71","a72","a73","a74","a75","a76","a77","a78","a79"); } \
  if ((MT) == 1) { ARD16(o0,"a16","a17","a18","a19","a20","a21","a22","a23","a24","a25","a26","a27","a28","a29","a30","a31"); \
                   ARD16(o1,"a80","a81","a82","a83","a84","a85","a86","a87","a88","a89","a90","a91","a92","a93","a94","a95"); } \
  if ((MT) == 2) { ARD16(o0,"a32","a33","a34","a35","a36","a37","a38","a39","a40","a41","a42","a43","a44","a45","a46","a47"); \
                   ARD16(o1,"a96","a97","a98","a99","a100","a101","a102","a103","a104","a105","a106","a107","a108","a109","a110","a111"); } \
  if ((MT) == 3) { ARD16(o0,"a48","a49","a50","a51","a52","a53","a54","a55","a56","a57","a58","a59","a60","a61","a62","a63"); \
                   ARD16(o1,"a112","a113","a114","a115","a116","a117","a118","a119","a120","a121","a122","a123","a124","a125","a126","a127"); } \
  _Pragma("unroll") for (int k = 0; k < 8; ++k) { \
    float s0 = g1 ? o0[k] : o0[k + 8];   /* send what the partner needs */ \
    float s1 = g1 ? o1[k] : o1[k + 8]; \
    r0[k] = __shfl_xor(s0, 16, 64); \
    r1[k] = __shfl_xor(s1, 16, 64); \
  } \
  _Pragma("unroll") for (int k = 0; k < 8; ++k) { \
    float pf = g1 ? r0[k] : o0[k]; \
    float pi = g1 ? o0[k + 8] : r0[k]; \
    float pc = g1 ? r1[k] : o1[k]; \
    float po = g1 ? o1[k + 8] : r1[k]; \
    const int b = rbw + (MT) * 32 + (k & 3) + 8 * (k >> 2); \
    pf += Bgf; pi += Bgi; pc += Bgc; po += Bgo; \
    float fg = 1.f / (1.f + __expf(-pf)); \
    float ig = 1.f / (1.f + __expf(-pi)); \
    float ct = 2.f / (1.f + __expf(-2.f * pc)) - 1.f; \
    float og = 1.f / (1.f + __expf(-po)); \
    float cn = fg * c_prev[(size_t)b * 1024 + hcol] + ig * ct; \
    float hn = og * (2.f / (1.f + __expf(-2.f * cn)) - 1.f); \
    out[(size_t)b * 1024 + hcol] = hn; \
    out[(size_t)4194304 + (size_t)b * 1024 + hcol] = cn; \
  } \
} while (0)

__global__ __launch_bounds__(512, 2) void lstm_gemm(
    const unsigned short* __restrict__ X, const unsigned short* __restrict__ Wct,
    const float* __restrict__ c_prev,
    const float* __restrict__ bfv, const float* __restrict__ biv,
    const float* __restrict__ bcv, const float* __restrict__ bov,
    float* __restrict__ out) {
  extern __shared__ __align__(16) char smem[];
  const int tid = threadIdx.x;
  const int lane = tid & 63, w = tid >> 6;
  const int wm = w >> 2, wn = w & 3;
  const int l31 = lane & 31, l7 = lane & 7, h5 = lane >> 5;
  const int g1 = (lane >> 4) & 1;

  // XCD-locality swizzle (as R8): XCD (bid&7) -> 128-h slab x 16 M-tiles
  const int bid = blockIdx.x;
  const int xcd = bid & 7, idx = bid >> 3;
  const int row0 = (idx & 15) * 256;
  const int h0 = (xcd * 2 + (idx >> 4)) * 64;

  const unsigned lds0 = (unsigned)(size_t)((__attribute__((address_space(3))) char*)smem);

  // fragment read addresses. 32x32x16 frag: lane holds row l31, k = h5*8..+7
  // of kstep ks -> byte = ks*32 + h5*16 -> slot s = 2*ks + h5, XOR (row&7)=l7.
  unsigned vA[4], vB[4];
  {
    const unsigned aArow = lds0 + (unsigned)(wm * 128 + l31) * 128;
    const unsigned aBrow = lds0 + 65536 + (unsigned)(wn * 64 + l31) * 128;
    #pragma unroll
    for (int ks = 0; ks < 4; ++ks) {
      const unsigned sw = (unsigned)(((2 * ks + h5) ^ l7) << 4);
      vA[ks] = aArow + sw;
      vB[ks] = aBrow + sw;
    }
  }

  // staging: wave w covers chunk rows w*16..w*16+15; linear dest, pre-swz src
  const int stbase = w * 2048 + lane * 16;
  const int rA0 = w * 16 + (lane >> 3), rA1 = rA0 + 8;
  const int ssA = (lane & 7) ^ (rA0 & 7);
  const unsigned short* pA0 = X + (size_t)(row0 + rA0) * 2048 + ssA * 8;
  const unsigned short* pA1 = X + (size_t)(row0 + rA1) * 2048 + ssA * 8;
  auto wrow = [&](int C) { return (((C >> 4) & 3) << 10) + h0 + ((C >> 6) << 4) + (C & 15); };
  const unsigned short* pB00 = Wct + (size_t)wrow(rA0) * 2048 + ssA * 8;
  const unsigned short* pB01 = Wct + (size_t)wrow(rA1) * 2048 + ssA * 8;
  const unsigned short* pB10 = Wct + (size_t)wrow(128 + rA0) * 2048 + ssA * 8;
  const unsigned short* pB11 = Wct + (size_t)wrow(128 + rA1) * 2048 + ssA * 8;

  AINIT();

  bfrag8 Ab0[4], Ab1[4], Bb0[4], Bb1[4];

  // prologue: stage even KT (buf0) + B-odd (buf1); read PH1's frags
  STAGE_A(0, 0, 0); STAGE_A(0, 1, 0);    // Ae (4)
  STAGE_B(0, 0);                          // Be (4)
  STAGE_B(1, 1);                          // Bo (4) stays in flight
  VMCNT(4);
  BARRIER();
  READ_A4(Ab0, 0, 0, 0);                  // A[mh0, e, kh0]
  READ_B4(Bb0, 0, 0);                     // B[e, kh0]

  #pragma unroll 1
  for (int t = 0; t < 16; ++t) {
    const int kt1 = 2 * t + 1, kt2 = 2 * t + 2, kt3 = 2 * t + 3;
    // PH1: cluster(e,kh0,mh0) | read A[mh1,e,kh0] | stage Ao
    READ_A4(Ab1, 0, 1, 0);
    STAGE_A(1, 0, kt1); STAGE_A(1, 1, kt1);
    BARRIER(); LGKM(4);
    CL_MH0(Ab0, Bb0);
    // PH2: cluster(e,kh0,mh1) | read A[mh0,e,kh1] + B[e,kh1]
    READ_A4(Ab0, 0, 0, 1);
    READ_B4(Bb1, 0, 1);
    BARRIER(); LGKM(8);
    CL_MH1(Ab1, Bb0);
    // PH3: cluster(e,kh1,mh0) | read A[mh1,e,kh1] | drain odd staging
    READ_A4(Ab1, 0, 1, 1);
    VMCNT(0);
    BARRIER(); LGKM(4);
    CL_MH0(Ab0, Bb1);
    // PH4: cluster(e,kh1,mh1) | read A[mh0,o,kh0] + B[o,kh0] | stage Be'
    READ_A4(Ab0, 1, 0, 0);
    READ_B4(Bb0, 1, 0);
    STAGE_B(0, kt2);
    BARRIER(); LGKM(8);
    CL_MH1(Ab1, Bb1);
    // PH5: cluster(o,kh0,mh0) | read A[mh1,o,kh0] | stage Ae'
    READ_A4(Ab1, 1, 1, 0);
    STAGE_A(0, 0, kt2); STAGE_A(0, 1, kt2);
    BARRIER(); LGKM(4);
    CL_MH0(Ab0, Bb0);
    // PH6: cluster(o,kh0,mh1) | read A[mh0,o,kh1] + B[o,kh1]
    READ_A4(Ab0, 1, 0, 1);
    READ_B4(Bb1, 1, 1);
    BARRIER(); LGKM(8);
    CL_MH1(Ab1, Bb0);
    // PH7: cluster(o,kh1,mh0) | read A[mh1,o,kh1] | drain even staging
    READ_A4(Ab1, 1, 1, 1);
    VMCNT(0);
    BARRIER(); LGKM(4);
    CL_MH0(Ab0, Bb1);
    // PH8: cluster(o,kh1,mh1) | read A[mh0,e',kh0] + B[e',kh0] | stage Bo'
    READ_A4(Ab0, 0, 0, 0);
    READ_B4(Bb0, 0, 0);
    STAGE_B(1, kt3);
    BARRIER(); LGKM(8);
    CL_MH1(Ab1, Bb1);
  }
  VMCNT(0); LGKM(0);
  asm volatile("s_nop 7\n\ts_nop 7\n\ts_nop 7");  // MFMA -> accvgpr_read guard

  // epilogue. C/D (32x32): col = l31, row = (r&3)+8*(r>>2)+4*h5.
  // col c = wn*64 + nt*32 + l31 -> gate = 2*nt + g1, h = h0+wn*16+(l31&15)
  const int hcol = h0 + wn * 16 + (lane & 15);
  const float Bgf = bfv[hcol], Bgi = biv[hcol], Bgc = bcv[hcol], Bgo = bov[hcol];
  const int rbw = row0 + wm * 128 + 16 * g1 + 4 * h5;
  EPI_MT(0);
  EPI_MT(1);
  EPI_MT(2);
  EPI_MT(3);
}

extern "C" void kernel_launch(void* const* d_in, const int* in_sizes, int n_in,
                              void* d_out, int out_size, void* d_ws, size_t ws_size,
                              hipStream_t stream) {
  const float* inputs = (const float*)d_in[0];
  const float* h_prev = (const float*)d_in[1];
  const float* c_prev = (const float*)d_in[2];
  const float* Wf = (const float*)d_in[3];
  const float* Uf = (const float*)d_in[4];
  const float* bf = (const float*)d_in[5];
  const float* Wi = (const float*)d_in[6];
  const float* Ui = (const float*)d_in[7];
  const float* bi = (const float*)d_in[8];
  const float* Wc = (const float*)d_in[9];
  const float* Uc = (const float*)d_in[10];
  const float* bc = (const float*)d_in[11];
  const float* Wo = (const float*)d_in[12];
  const float* Uo = (const float*)d_in[13];
  const float* bo = (const float*)d_in[14];
  float* out = (float*)d_out;

  unsigned short* X   = (unsigned short*)d_ws;                 // 16 MB
  unsigned short* Wct = X + (size_t)4096 * 2048;               // 16 MB

  (void)hipFuncSetAttribute(reinterpret_cast<const void*>(lstm_gemm),
                            hipFuncAttributeMaxDynamicSharedMemorySize, 131072);

  prep_x<<<4096, 256, 0, stream>>>(inputs, h_prev, X);
  prep_w<<<2048, 256, 0, stream>>>(Wf, Uf, Wi, Ui, Wc, Uc, Wo, Uo, Wct);
  lstm_gemm<<<256, 512, 131072, stream>>>(X, Wct, c_prev, bf, bi, bc, bo, out);
}

// Round 12
// 86.001 us; speedup vs baseline: 1.1908x; 1.0964x over previous
//
#include <hip/hip_runtime.h>

// LSTM cell, B=4096, D=H=1024.
//   X = [inputs | h_prev]  (4096 x 2048) bf16   (ws, 16 MB)
//   Wct[g][h][k] = concat(W_g,U_g)^T bf16       (ws, 16 MB)
//   8-phase 256x256 fused GEMM (4 gates x 64 h per block) + LSTM epilogue.
//   R12 = R8's verified lstm_gemm (16x16x32, conflict-free swizzle) +
//   R9's verified single-launch fused prep (one less launch gap).
//   R10/R11 closed: 32x32 fragments are a structural 4-way LDS bank conflict
//   under gload_lds-linear staging (4.0 extra cyc per b128, measured).

typedef __attribute__((ext_vector_type(8))) short bfrag8;   // 8 bf16 (4 VGPRs)

__device__ __forceinline__ unsigned int f2bf(float f) {
  unsigned int u = __builtin_bit_cast(unsigned int, f);
  unsigned int r = (u + 0x7fffu + ((u >> 16) & 1u)) >> 16;
  return r & 0xffffu;
}

// ------------- fused prep: X cast/concat + W transpose/cast ------------------
__global__ __launch_bounds__(256) void prep_all(
    const float* __restrict__ inputs, const float* __restrict__ h_prev,
    const float* __restrict__ s0, const float* __restrict__ s1,
    const float* __restrict__ s2, const float* __restrict__ s3,
    const float* __restrict__ s4, const float* __restrict__ s5,
    const float* __restrict__ s6, const float* __restrict__ s7,
    unsigned short* __restrict__ X, unsigned short* __restrict__ Wct) {
  const int bidAll = blockIdx.x;
  const int tid = threadIdx.x;
  if (bidAll < 4096) {
    int idx = bidAll * 256 + tid;
    int b  = idx >> 8;
    int k8 = (idx & 255) * 8;
    const float* src = (k8 < 1024) ? (inputs + (size_t)b * 1024 + k8)
                                   : (h_prev + (size_t)b * 1024 + (k8 - 1024));
    float4 v0 = ((const float4*)src)[0];
    float4 v1 = ((const float4*)src)[1];
    uint4 o;
    o.x = f2bf(v0.x) | (f2bf(v0.y) << 16);
    o.y = f2bf(v0.z) | (f2bf(v0.w) << 16);
    o.z = f2bf(v1.x) | (f2bf(v1.y) << 16);
    o.w = f2bf(v1.z) | (f2bf(v1.w) << 16);
    *(uint4*)(X + (size_t)b * 2048 + k8) = o;
    return;
  }
  int blk = bidAll - 4096;
  int m = blk >> 8;
  const float* src = (m == 0) ? s0 : (m == 1) ? s1 : (m == 2) ? s2 : (m == 3) ? s3
                   : (m == 4) ? s4 : (m == 5) ? s5 : (m == 6) ? s6 : s7;
  int g = m >> 1, half = m & 1;
  unsigned short* dst = Wct + (size_t)g * 1024 * 2048 + (size_t)half * 1024;
  int t = blk & 255;
  int k0 = (t >> 4) * 64;
  int h0 = (t & 15) * 64;
  __shared__ float lt[64][68];
  #pragma unroll
  for (int it = 0; it < 4; ++it) {
    int r  = (tid >> 4) + it * 16;
    int c4 = (tid & 15) * 4;
    float4 v = *(const float4*)(src + (size_t)(k0 + r) * 1024 + h0 + c4);
    lt[r][c4 + 0] = v.x; lt[r][c4 + 1] = v.y; lt[r][c4 + 2] = v.z; lt[r][c4 + 3] = v.w;
  }
  __syncthreads();
  #pragma unroll
  for (int it = 0; it < 4; ++it) {
    int hh  = (tid >> 4) + it * 16;
    int kk4 = (tid & 15) * 4;
    uint2 o;
    o.x = f2bf(lt[kk4 + 0][hh]) | (f2bf(lt[kk4 + 1][hh]) << 16);
    o.y = f2bf(lt[kk4 + 2][hh]) | (f2bf(lt[kk4 + 3][hh]) << 16);
    *(uint2*)(dst + (size_t)(h0 + hh) * 2048 + k0 + kk4) = o;
  }
}

// ---------------- 8-phase fused 4-gate GEMM + LSTM epilogue ------------------

#define FENCE() asm volatile("" ::: "memory")
#define BARRIER() do { FENCE(); __builtin_amdgcn_s_barrier(); FENCE(); } while (0)
#define VMCNT(n) asm volatile("s_waitcnt vmcnt(" #n ")" ::: "memory")
#define LGKM(n) asm volatile("s_waitcnt lgkmcnt(" #n ")" ::: "memory")
#define GLOAD16(gp, lp) __builtin_amdgcn_global_load_lds( \
    (const __attribute__((address_space(1))) unsigned int*)(gp), \
    (__attribute__((address_space(3))) unsigned int*)(lp), 16, 0, 0)
#define DSR(dst, addr, off) asm volatile("ds_read_b128 %0, %1 offset:%c2" \
    : "=v"(dst) : "v"(addr), "n"(off))

// full AGPR clobber list (keeps the allocator out of a0-a127)
#define AC "a0","a1","a2","a3","a4","a5","a6","a7","a8","a9","a10","a11","a12","a13","a14","a15", \
 "a16","a17","a18","a19","a20","a21","a22","a23","a24","a25","a26","a27","a28","a29","a30","a31", \
 "a32","a33","a34","a35","a36","a37","a38","a39","a40","a41","a42","a43","a44","a45","a46","a47", \
 "a48","a49","a50","a51","a52","a53","a54","a55","a56","a57","a58","a59","a60","a61","a62","a63", \
 "a64","a65","a66","a67","a68","a69","a70","a71","a72","a73","a74","a75","a76","a77","a78","a79", \
 "a80","a81","a82","a83","a84","a85","a86","a87","a88","a89","a90","a91","a92","a93","a94","a95", \
 "a96","a97","a98","a99","a100","a101","a102","a103","a104","a105","a106","a107","a108","a109","a110","a111", \
 "a112","a113","a114","a115","a116","a117","a118","a119","a120","a121","a122","a123","a124","a125","a126","a127"

#define WZ(n) "v_accvgpr_write_b32 a" #n ", 0\n\t"
#define AINIT() asm volatile( \
 WZ(0)WZ(1)WZ(2)WZ(3)WZ(4)WZ(5)WZ(6)WZ(7)WZ(8)WZ(9)WZ(10)WZ(11)WZ(12)WZ(13)WZ(14)WZ(15) \
 WZ(16)WZ(17)WZ(18)WZ(19)WZ(20)WZ(21)WZ(22)WZ(23)WZ(24)WZ(25)WZ(26)WZ(27)WZ(28)WZ(29)WZ(30)WZ(31) \
 WZ(32)WZ(33)WZ(34)WZ(35)WZ(36)WZ(37)WZ(38)WZ(39)WZ(40)WZ(41)WZ(42)WZ(43)WZ(44)WZ(45)WZ(46)WZ(47) \
 WZ(48)WZ(49)WZ(50)WZ(51)WZ(52)WZ(53)WZ(54)WZ(55)WZ(56)WZ(57)WZ(58)WZ(59)WZ(60)WZ(61)WZ(62)WZ(63) \
 WZ(64)WZ(65)WZ(66)WZ(67)WZ(68)WZ(69)WZ(70)WZ(71)WZ(72)WZ(73)WZ(74)WZ(75)WZ(76)WZ(77)WZ(78)WZ(79) \
 WZ(80)WZ(81)WZ(82)WZ(83)WZ(84)WZ(85)WZ(86)WZ(87)WZ(88)WZ(89)WZ(90)WZ(91)WZ(92)WZ(93)WZ(94)WZ(95) \
 WZ(96)WZ(97)WZ(98)WZ(99)WZ(100)WZ(101)WZ(102)WZ(103)WZ(104)WZ(105)WZ(106)WZ(107)WZ(108)WZ(109)WZ(110)WZ(111) \
 WZ(112)WZ(113)WZ(114)WZ(115)WZ(116)WZ(117)WZ(118)WZ(119)WZ(120)WZ(121)WZ(122)WZ(123)WZ(124)WZ(125)WZ(126)WZ(127) \
 ::: AC)

#define MFMA_ONE(BR, AF, BF) asm volatile( \
    "v_mfma_f32_16x16x32_bf16 a[" BR "], %0, %1, a[" BR "]" \
    :: "v"(AF), "v"(BF) : AC)

// 16 MFMA: acc[g][MH*4+mi] += A4[mi] * B4[g]; bases (g*8+MH*4+mi)*4
#define CLUSTER16(A4, B4, R00,R01,R02,R03, R10,R11,R12,R13, R20,R21,R22,R23, R30,R31,R32,R33) do { \
  __builtin_amdgcn_s_setprio(1); \
  MFMA_ONE(R00, (A4)[0], (B4)[0]); MFMA_ONE(R01, (A4)[1], (B4)[0]); \
  MFMA_ONE(R02, (A4)[2], (B4)[0]); MFMA_ONE(R03, (A4)[3], (B4)[0]); \
  MFMA_ONE(R10, (A4)[0], (B4)[1]); MFMA_ONE(R11, (A4)[1], (B4)[1]); \
  MFMA_ONE(R12, (A4)[2], (B4)[1]); MFMA_ONE(R13, (A4)[3], (B4)[1]); \
  MFMA_ONE(R20, (A4)[0], (B4)[2]); MFMA_ONE(R21, (A4)[1], (B4)[2]); \
  MFMA_ONE(R22, (A4)[2], (B4)[2]); MFMA_ONE(R23, (A4)[3], (B4)[2]); \
  MFMA_ONE(R30, (A4)[0], (B4)[3]); MFMA_ONE(R31, (A4)[1], (B4)[3]); \
  MFMA_ONE(R32, (A4)[2], (B4)[3]); MFMA_ONE(R33, (A4)[3], (B4)[3]); \
  __builtin_amdgcn_s_setprio(0); \
} while (0)

#define CL_MH0(A4, B4) CLUSTER16(A4, B4, \
  "0:3","4:7","8:11","12:15", "32:35","36:39","40:43","44:47", \
  "64:67","68:71","72:75","76:79", "96:99","100:103","104:107","108:111")
#define CL_MH1(A4, B4) CLUSTER16(A4, B4, \
  "16:19","20:23","24:27","28:31", "48:51","52:55","56:59","60:63", \
  "80:83","84:87","88:91","92:95", "112:115","116:119","120:123","124:127")

// reads: A frag (mh, mi, kk) at row (wm*128+mh*64+mi*16+u), byte row*128+sw(kk)
#define READ_A4(arr, BUF, MH, ABASE) do { \
  DSR(arr[0], ABASE, (BUF)*32768 + (MH)*8192 + 0);    \
  DSR(arr[1], ABASE, (BUF)*32768 + (MH)*8192 + 2048); \
  DSR(arr[2], ABASE, (BUF)*32768 + (MH)*8192 + 4096); \
  DSR(arr[3], ABASE, (BUF)*32768 + (MH)*8192 + 6144); \
} while (0)

#define READ_B4N(arr, BUF, BBASE) do { \
  DSR(arr[0], BBASE, (BUF)*32768 + 0);    \
  DSR(arr[1], BBASE, (BUF)*32768 + 2048); \
  DSR(arr[2], BBASE, (BUF)*32768 + 4096); \
  DSR(arr[3], BBASE, (BUF)*32768 + 6144); \
} while (0)

#define STAGE_A(BUF, H, kt) do { int _kb = ((kt) < 32 ? (kt) : 31) * 64; \
  GLOAD16(pA0 + (size_t)(H) * 262144 + _kb, smem + (BUF)*32768 + (H)*16384 + stbase); \
  GLOAD16(pA1 + (size_t)(H) * 262144 + _kb, smem + (BUF)*32768 + (H)*16384 + stbase + 1024); \
} while (0)

#define STAGE_B(BUF, kt) do { int _kb = ((kt) < 32 ? (kt) : 31) * 64; \
  GLOAD16(pB00 + _kb, smem + 65536 + (BUF)*32768 + stbase); \
  GLOAD16(pB01 + _kb, smem + 65536 + (BUF)*32768 + stbase + 1024); \
  GLOAD16(pB10 + _kb, smem + 65536 + (BUF)*32768 + 16384 + stbase); \
  GLOAD16(pB11 + _kb, smem + 65536 + (BUF)*32768 + 16384 + stbase + 1024); \
} while (0)

#define ARD(X, RS) asm volatile("v_accvgpr_read_b32 %0, " RS : "=v"(X))

#define EPI_M(Mi, F0,F1,F2,F3, I0,I1,I2,I3, C0,C1,C2,C3, O0,O1,O2,O3) do { \
  float pf[4], pi[4], pc[4], po[4]; \
  ARD(pf[0],F0); ARD(pf[1],F1); ARD(pf[2],F2); ARD(pf[3],F3); \
  ARD(pi[0],I0); ARD(pi[1],I1); ARD(pi[2],I2); ARD(pi[3],I3); \
  ARD(pc[0],C0); ARD(pc[1],C1); ARD(pc[2],C2); ARD(pc[3],C3); \
  ARD(po[0],O0); ARD(po[1],O1); ARD(po[2],O2); ARD(po[3],O3); \
  _Pragma("unroll") for (int j = 0; j < 4; ++j) { \
    const int b = rbw + (Mi) * 16 + q * 4 + j; \
    float xf = pf[j] + Bgf, xi = pi[j] + Bgi, xc = pc[j] + Bgc, xo = po[j] + Bgo; \
    float fg = 1.f / (1.f + __expf(-xf)); \
    float ig = 1.f / (1.f + __expf(-xi)); \
    float ct = 2.f / (1.f + __expf(-2.f * xc)) - 1.f; \
    float og = 1.f / (1.f + __expf(-xo)); \
    float cn = fg * c_prev[(size_t)b * 1024 + hcol] + ig * ct; \
    float hn = og * (2.f / (1.f + __expf(-2.f * cn)) - 1.f); \
    out[(size_t)b * 1024 + hcol] = hn; \
    out[(size_t)4194304 + (size_t)b * 1024 + hcol] = cn; \
  } \
} while (0)

__global__ __launch_bounds__(512, 2) void lstm_gemm(
    const unsigned short* __restrict__ X, const unsigned short* __restrict__ Wct,
    const float* __restrict__ c_prev,
    const float* __restrict__ bfv, const float* __restrict__ biv,
    const float* __restrict__ bcv, const float* __restrict__ bov,
    float* __restrict__ out) {
  extern __shared__ __align__(16) char smem[];
  const int tid = threadIdx.x;
  const int lane = tid & 63, w = tid >> 6;
  const int u = lane & 15, q = (lane >> 4) & 3;
  const int wm = w >> 2, wn = w & 3;

  // XCD-locality swizzle: XCD (bid&7) -> 128-h slab x 16 M-tiles
  const int bid = blockIdx.x;
  const int xcd = bid & 7, idx = bid >> 3;
  const int row0 = (idx & 15) * 256;
  const int h0 = (xcd * 2 + (idx >> 4)) * 64;

  const unsigned lds0 = (unsigned)(size_t)((__attribute__((address_space(3))) char*)smem);

  // fragment read bases: sw(kk) = ((kk*4+q) ^ (u&7)) << 4
  const int sw0 = (q ^ (u & 7)) << 4;
  const int sw1 = ((q + 4) ^ (u & 7)) << 4;
  const unsigned aA0 = lds0 + wm * 16384 + u * 128 + sw0;           // A, kk0
  const unsigned aA1 = lds0 + wm * 16384 + u * 128 + sw1;           // A, kk1
  const unsigned aB0 = lds0 + 65536 + (wn * 64 + u) * 128 + sw0;    // B, kk0
  const unsigned aB1 = lds0 + 65536 + (wn * 64 + u) * 128 + sw1;    // B, kk1

  // staging: wave w covers chunk rows w*16..w*16+15; linear dest, pre-swz src
  const int stbase = w * 2048 + lane * 16;
  const int rA0 = w * 16 + (lane >> 3), rA1 = rA0 + 8;
  const int ssA = (lane & 7) ^ (rA0 & 7);
  const unsigned short* pA0 = X + (size_t)(row0 + rA0) * 2048 + ssA * 8;
  const unsigned short* pA1 = X + (size_t)(row0 + rA1) * 2048 + ssA * 8;
  auto wrow = [&](int C) { return (((C >> 4) & 3) << 10) + h0 + ((C >> 6) << 4) + (C & 15); };
  const unsigned short* pB00 = Wct + (size_t)wrow(rA0) * 2048 + ssA * 8;
  const unsigned short* pB01 = Wct + (size_t)wrow(rA1) * 2048 + ssA * 8;
  const unsigned short* pB10 = Wct + (size_t)wrow(128 + rA0) * 2048 + ssA * 8;
  const unsigned short* pB11 = Wct + (size_t)wrow(128 + rA1) * 2048 + ssA * 8;

  AINIT();

  bfrag8 Ab0[4], Ab1[4], Bb0[4], Bb1[4];

  // prologue: stage even KT (buf0) + B-odd (buf1); read PH1's frags
  STAGE_A(0, 0, 0); STAGE_A(0, 1, 0);    // Ae (4)
  STAGE_B(0, 0);                          // Be (4)
  STAGE_B(1, 1);                          // Bo (4) stays in flight
  VMCNT(4);
  BARRIER();
  READ_A4(Ab0, 0, 0, aA0);                // A[mh0,e,kk0]
  READ_B4N(Bb0, 0, aB0);                  // B[e,kk0]

  #pragma unroll 1
  for (int t = 0; t < 16; ++t) {
    const int kt1 = 2 * t + 1, kt2 = 2 * t + 2, kt3 = 2 * t + 3;
    // PH1: cluster(e,kk0,mh0) | read A[mh1,e,kk0] | stage Ao
    READ_A4(Ab1, 0, 1, aA0);
    STAGE_A(1, 0, kt1); STAGE_A(1, 1, kt1);
    BARRIER(); LGKM(4);
    CL_MH0(Ab0, Bb0);
    // PH2: cluster(e,kk0,mh1) | read A[mh0,e,kk1] + B[e,kk1]
    READ_A4(Ab0, 0, 0, aA1);
    READ_B4N(Bb1, 0, aB1);
    BARRIER(); LGKM(8);
    CL_MH1(Ab1, Bb0);
    // PH3: cluster(e,kk1,mh0) | read A[mh1,e,kk1] | drain odd staging
    READ_A4(Ab1, 0, 1, aA1);
    VMCNT(0);
    BARRIER(); LGKM(4);
    CL_MH0(Ab0, Bb1);
    // PH4: cluster(e,kk1,mh1) | read A[mh0,o,kk0] + B[o,kk0] | stage Be'
    READ_A4(Ab0, 1, 0, aA0);
    READ_B4N(Bb0, 1, aB0);
    STAGE_B(0, kt2);
    BARRIER(); LGKM(8);
    CL_MH1(Ab1, Bb1);
    // PH5: cluster(o,kk0,mh0) | read A[mh1,o,kk0] | stage Ae'
    READ_A4(Ab1, 1, 1, aA0);
    STAGE_A(0, 0, kt2); STAGE_A(0, 1, kt2);
    BARRIER(); LGKM(4);
    CL_MH0(Ab0, Bb0);
    // PH6: cluster(o,kk0,mh1) | read A[mh0,o,kk1] + B[o,kk1]
    READ_A4(Ab0, 1, 0, aA1);
    READ_B4N(Bb1, 1, aB1);
    BARRIER(); LGKM(8);
    CL_MH1(Ab1, Bb0);
    // PH7: cluster(o,kk1,mh0) | read A[mh1,o,kk1] | drain even staging
    READ_A4(Ab1, 1, 1, aA1);
    VMCNT(0);
    BARRIER(); LGKM(4);
    CL_MH0(Ab0, Bb1);
    // PH8: cluster(o,kk1,mh1) | read A[mh0,e',kk0] + B[e',kk0] | stage Bo'
    READ_A4(Ab0, 0, 0, aA0);
    READ_B4N(Bb0, 0, aB0);
    STAGE_B(1, kt3);
    BARRIER(); LGKM(8);
    CL_MH1(Ab1, Bb1);
  }
  VMCNT(0); LGKM(0);
  asm volatile("s_nop 7\n\ts_nop 7");   // MFMA -> accvgpr_read hazard guard

  const int hcol = h0 + wn * 16 + u;
  const float Bgf = bfv[hcol], Bgi = biv[hcol], Bgc = bcv[hcol], Bgo = bov[hcol];
  const int rbw = row0 + wm * 128;
  EPI_M(0, "a0","a1","a2","a3",     "a32","a33","a34","a35",
           "a64","a65","a66","a67", "a96","a97","a98","a99");
  EPI_M(1, "a4","a5","a6","a7",     "a36","a37","a38","a39",
           "a68","a69","a70","a71", "a100","a101","a102","a103");
  EPI_M(2, "a8","a9","a10","a11",   "a40","a41","a42","a43",
           "a72","a73","a74","a75", "a104","a105","a106","a107");
  EPI_M(3, "a12","a13","a14","a15", "a44","a45","a46","a47",
           "a76","a77","a78","a79", "a108","a109","a110","a111");
  EPI_M(4, "a16","a17","a18","a19", "a48","a49","a50","a51",
           "a80","a81","a82","a83", "a112","a113","a114","a115");
  EPI_M(5, "a20","a21","a22","a23", "a52","a53","a54","a55",
           "a84","a85","a86","a87", "a116","a117","a118","a119");
  EPI_M(6, "a24","a25","a26","a27", "a56","a57","a58","a59",
           "a88","a89","a90","a91", "a120","a121","a122","a123");
  EPI_M(7, "a28","a29","a30","a31", "a60","a61","a62","a63",
           "a92","a93","a94","a95", "a124","a125","a126","a127");
}

extern "C" void kernel_launch(void* const* d_in, const int* in_sizes, int n_in,
                              void* d_out, int out_size, void* d_ws, size_t ws_size,
                              hipStream_t stream) {
  const float* inputs = (const float*)d_in[0];
  const float* h_prev = (const float*)d_in[1];
  const float* c_prev = (const float*)d_in[2];
  const float* Wf = (const float*)d_in[3];
  const float* Uf = (const float*)d_in[4];
  const float* bf = (const float*)d_in[5];
  const float* Wi = (const float*)d_in[6];
  const float* Ui = (const float*)d_in[7];
  const float* bi = (const float*)d_in[8];
  const float* Wc = (const float*)d_in[9];
  const float* Uc = (const float*)d_in[10];
  const float* bc = (const float*)d_in[11];
  const float* Wo = (const float*)d_in[12];
  const float* Uo = (const float*)d_in[13];
  const float* bo = (const float*)d_in[14];
  float* out = (float*)d_out;

  unsigned short* X   = (unsigned short*)d_ws;                 // 16 MB
  unsigned short* Wct = X + (size_t)4096 * 2048;               // 16 MB

  (void)hipFuncSetAttribute(reinterpret_cast<const void*>(lstm_gemm),
                            hipFuncAttributeMaxDynamicSharedMemorySize, 131072);

  prep_all<<<6144, 256, 0, stream>>>(inputs, h_prev,
                                     Wf, Uf, Wi, Ui, Wc, Uc, Wo, Uo, X, Wct);
  lstm_gemm<<<256, 512, 131072, stream>>>(X, Wct, c_prev, bf, bi, bc, bo, out);
}